// Round 1
// baseline (220.311 us; speedup 1.0000x reference)
//
#include <hip/hip_runtime.h>

// GQA attention fused pipeline for MI355X (gfx950).
// Pipeline: cvt(fp32->bf16) -> GEMM(QKV proj) -> RoPE/scatter + V-transpose
//           -> flash attention (bf16 MFMA 16x16x32) -> GEMM(out proj, fp32 out).

typedef __bf16 bf16x8 __attribute__((ext_vector_type(8)));
typedef float f32x4 __attribute__((ext_vector_type(4)));
typedef unsigned short ushort4v __attribute__((ext_vector_type(4)));
typedef unsigned short ushort8v __attribute__((ext_vector_type(8)));
typedef unsigned short u16;

#define DEVINL __device__ __forceinline__

DEVINL float bf2f(u16 u) {
  unsigned int x = ((unsigned int)u) << 16;
  return __builtin_bit_cast(float, x);
}
DEVINL u16 f2bf(float f) {  // RTNE
  unsigned int x = __builtin_bit_cast(unsigned int, f);
  x += 0x7fffu + ((x >> 16) & 1u);
  return (u16)(x >> 16);
}

constexpr int Bb = 2, Tt = 2048, Dd = 1024, QH = 16, KVH = 4, HD = 64;
// fold softmax scale (1/sqrt(64)) and log2(e) into Q so we can use exp2f
constexpr float SCALE_L2E = 0.125f * 1.44269504088896340736f;

// ---------------------------------------------------------------- convert
__global__ void cvt_f32_to_bf16(const float* __restrict__ in, u16* __restrict__ out, int n4) {
  int i = blockIdx.x * blockDim.x + threadIdx.x;
  if (i >= n4) return;
  float4 v = reinterpret_cast<const float4*>(in)[i];
  ushort4v o = {f2bf(v.x), f2bf(v.y), f2bf(v.z), f2bf(v.w)};
  reinterpret_cast<ushort4v*>(out)[i] = o;
}

// ---------------------------------------------------------------- GEMM C = A(M,K) @ B(N,K)^T
// 128x128 tile, BK=64, 4 waves (each 64x64 = 4x4 frags of 16x16x32 bf16 MFMA).
// LDS chunks XOR-swizzled (chunk ^= row&7) so ds_read_b128 frag reads are conflict-free.
template <bool OUT_F32>
__global__ __launch_bounds__(256) void gemm_bt(const u16* __restrict__ A,
                                               const u16* __restrict__ Bw,
                                               void* __restrict__ Cout, int M, int N, int K) {
  __shared__ alignas(16) u16 lA[128 * 64];
  __shared__ alignas(16) u16 lB[128 * 64];
  const int tid = threadIdx.x;
  const int w = tid >> 6, lane = tid & 63;
  const int r16 = lane & 15, g4 = lane >> 4;
  const int row0 = blockIdx.y * 128, col0 = blockIdx.x * 128;
  const int sr = tid >> 3, sc = tid & 7;  // staging: row-in-32-group, 16B chunk
  const int NT = K >> 6;

  bf16x8 ra[4], rb[4];
  f32x4 acc[4][4];
#pragma unroll
  for (int i = 0; i < 4; ++i)
#pragma unroll
    for (int j = 0; j < 4; ++j) acc[i][j] = f32x4{0.f, 0.f, 0.f, 0.f};

  const int wm = (w >> 1) * 64, wn = (w & 1) * 64;

  // prefetch k-tile 0 into registers
#pragma unroll
  for (int i = 0; i < 4; ++i) {
    int r = i * 32 + sr;
    ra[i] = *reinterpret_cast<const bf16x8*>(A + (size_t)(row0 + r) * K + sc * 8);
    rb[i] = *reinterpret_cast<const bf16x8*>(Bw + (size_t)(col0 + r) * K + sc * 8);
  }

  for (int kt = 0; kt < NT; ++kt) {
    __syncthreads();  // previous compute finished reading LDS
#pragma unroll
    for (int i = 0; i < 4; ++i) {
      int r = i * 32 + sr;
      int c = (sc ^ (r & 7)) * 8;  // swizzled 16B chunk
      *reinterpret_cast<bf16x8*>(&lA[r * 64 + c]) = ra[i];
      *reinterpret_cast<bf16x8*>(&lB[r * 64 + c]) = rb[i];
    }
    __syncthreads();
    if (kt + 1 < NT) {  // prefetch next tile, overlaps with MFMA below
      int k0 = (kt + 1) << 6;
#pragma unroll
      for (int i = 0; i < 4; ++i) {
        int r = i * 32 + sr;
        ra[i] = *reinterpret_cast<const bf16x8*>(A + (size_t)(row0 + r) * K + k0 + sc * 8);
        rb[i] = *reinterpret_cast<const bf16x8*>(Bw + (size_t)(col0 + r) * K + k0 + sc * 8);
      }
    }
#pragma unroll
    for (int kk = 0; kk < 2; ++kk) {
      bf16x8 af[4], bfr[4];
#pragma unroll
      for (int mf = 0; mf < 4; ++mf) {
        int r = wm + mf * 16 + r16;
        int c = ((kk * 4 + g4) ^ (r & 7)) * 8;
        af[mf] = *reinterpret_cast<const bf16x8*>(&lA[r * 64 + c]);
      }
#pragma unroll
      for (int nf = 0; nf < 4; ++nf) {
        int r = wn + nf * 16 + r16;
        int c = ((kk * 4 + g4) ^ (r & 7)) * 8;
        bfr[nf] = *reinterpret_cast<const bf16x8*>(&lB[r * 64 + c]);
      }
#pragma unroll
      for (int mf = 0; mf < 4; ++mf)
#pragma unroll
        for (int nf = 0; nf < 4; ++nf)
          acc[mf][nf] =
              __builtin_amdgcn_mfma_f32_16x16x32_bf16(af[mf], bfr[nf], acc[mf][nf], 0, 0, 0);
    }
  }

  // epilogue: C/D layout col=lane&15, row=(lane>>4)*4+reg
#pragma unroll
  for (int mf = 0; mf < 4; ++mf)
#pragma unroll
    for (int nf = 0; nf < 4; ++nf)
#pragma unroll
      for (int r = 0; r < 4; ++r) {
        size_t row = (size_t)(row0 + wm + mf * 16 + g4 * 4 + r);
        size_t col = (size_t)(col0 + wn + nf * 16 + r16);
        float v = acc[mf][nf][r];
        if (OUT_F32)
          reinterpret_cast<float*>(Cout)[row * N + col] = v;
        else
          reinterpret_cast<u16*>(Cout)[row * N + col] = f2bf(v);
      }
}

// ---------------------------------------------------------------- RoPE + scatter (q and k only)
// P = [4096][1536] bf16 (cols 0..1023 = q heads, 1024..1535 = interleaved k/v per kv-head).
// Q gets SCALE*log2e folded in. V handled by v_transpose.
__global__ void rope_scatter(const u16* __restrict__ P, const float* __restrict__ cosT,
                             const float* __restrict__ sinT, u16* __restrict__ Q,
                             u16* __restrict__ Kc) {
  int idx = blockIdx.x * 256 + threadIdx.x;
  if (idx >= (Bb * Tt) * 640) return;  // 512 q-pairs + 128 k-pairs per row
  int row = idx / 640, p = idx - row * 640;
  int b = row >> 11, t = row & 2047;
  int n, d;
  u16* outp;
  float scl;
  if (p < 512) {
    n = p * 2;
    int h = n >> 6;
    d = n & 63;
    outp = Q + ((size_t)(b * QH + h) * Tt + t) * HD + d;
    scl = SCALE_L2E;
  } else {
    int r2 = p - 512;
    int kvh = r2 >> 5, dp = r2 & 31;
    d = dp * 2;
    n = 1024 + kvh * 128 + d;  // 'which'==0 half of the kv block
    outp = Kc + ((size_t)(b * KVH + kvh) * Tt + t) * HD + d;
    scl = 1.0f;
  }
  unsigned int pv = *reinterpret_cast<const unsigned int*>(P + (size_t)row * 1536 + n);
  float v0 = bf2f((u16)(pv & 0xffffu)), v1 = bf2f((u16)(pv >> 16));
  float c = cosT[t * HD + d], s = sinT[t * HD + d];  // cos/sin repeated per pair
  float o0 = (v0 * c - v1 * s) * scl;
  float o1 = (v1 * c + v0 * s) * scl;
  unsigned int ob = (unsigned int)f2bf(o0) | ((unsigned int)f2bf(o1) << 16);
  *reinterpret_cast<unsigned int*>(outp) = ob;
}

// ---------------------------------------------------------------- V transpose: Vt[bh][d][t]
__global__ void v_transpose(const u16* __restrict__ P, u16* __restrict__ Vt) {
  __shared__ u16 tile[64][72];
  int bh = blockIdx.y;  // b*KVH + kvh
  int b = bh >> 2, kvh = bh & 3;
  int t0 = blockIdx.x * 64;
  int tid = threadIdx.x;
  int colbase = 1024 + kvh * 128 + 64;  // 'which'==1 half
#pragma unroll
  for (int j = 0; j < 4; ++j) {
    int rr = j * 16 + (tid >> 4);
    int cc = (tid & 15) * 4;
    *reinterpret_cast<uint2*>(&tile[rr][cc]) =
        *reinterpret_cast<const uint2*>(P + (size_t)(b * Tt + t0 + rr) * 1536 + colbase + cc);
  }
  __syncthreads();
  int d = tid >> 2, seg = tid & 3;
  size_t obase = ((size_t)bh * HD + d) * Tt + t0 + seg * 16;
#pragma unroll
  for (int jj = 0; jj < 2; ++jj) {
    ushort8v v;
#pragma unroll
    for (int i = 0; i < 8; ++i) v[i] = tile[seg * 16 + jj * 8 + i][d];
    *reinterpret_cast<ushort8v*>(Vt + obase + jj * 8) = v;
  }
}

// ---------------------------------------------------------------- flash attention
// block = 4 waves; each wave owns 32 q-rows (Q frags live in registers all tiles).
// 64-key tiles; K,Vt frag-loaded straight from global (L1/L2 resident);
// P round-trips through per-wave LDS (pad 72) to re-layout for the PV MFMA.
__global__ __launch_bounds__(256) void attn_fwd(const u16* __restrict__ Q,
                                                const u16* __restrict__ Kc,
                                                const u16* __restrict__ Vt,
                                                u16* __restrict__ Oa) {
  __shared__ alignas(16) u16 plds[4][32][72];
  const int tid = threadIdx.x;
  const int w = tid >> 6, lane = tid & 63;
  const int r16 = lane & 15, g4 = lane >> 4;
  const int h = blockIdx.y, b = blockIdx.z;
  const int kvh = h >> 2;
  const int t0 = blockIdx.x * 128 + w * 32;

  const u16* Qh = Q + (size_t)(b * QH + h) * Tt * HD;
  const u16* Kh = Kc + (size_t)(b * KVH + kvh) * Tt * HD;
  const u16* Vh = Vt + (size_t)(b * KVH + kvh) * HD * Tt;

  bf16x8 aq[2][2];
#pragma unroll
  for (int mf = 0; mf < 2; ++mf)
#pragma unroll
    for (int kf = 0; kf < 2; ++kf)
      aq[mf][kf] = *reinterpret_cast<const bf16x8*>(Qh + (size_t)(t0 + mf * 16 + r16) * HD +
                                                    kf * 32 + g4 * 8);

  float mrun[2][4], lp[2][4];
  f32x4 oacc[2][4];
#pragma unroll
  for (int mf = 0; mf < 2; ++mf)
#pragma unroll
    for (int r = 0; r < 4; ++r) {
      mrun[mf][r] = -__builtin_inff();
      lp[mf][r] = 0.f;
    }
#pragma unroll
  for (int mf = 0; mf < 2; ++mf)
#pragma unroll
    for (int df = 0; df < 4; ++df) oacc[mf][df] = f32x4{0.f, 0.f, 0.f, 0.f};

  for (int s0 = 0; s0 < Tt; s0 += 64) {
    bf16x8 bk[4][2];
#pragma unroll
    for (int nf = 0; nf < 4; ++nf)
#pragma unroll
      for (int kf = 0; kf < 2; ++kf)
        bk[nf][kf] = *reinterpret_cast<const bf16x8*>(Kh + (size_t)(s0 + nf * 16 + r16) * HD +
                                                      kf * 32 + g4 * 8);

    f32x4 sacc[2][4];
#pragma unroll
    for (int mf = 0; mf < 2; ++mf)
#pragma unroll
      for (int nf = 0; nf < 4; ++nf) sacc[mf][nf] = f32x4{0.f, 0.f, 0.f, 0.f};
#pragma unroll
    for (int nf = 0; nf < 4; ++nf)
#pragma unroll
      for (int mf = 0; mf < 2; ++mf)
#pragma unroll
        for (int kf = 0; kf < 2; ++kf)
          sacc[mf][nf] =
              __builtin_amdgcn_mfma_f32_16x16x32_bf16(aq[mf][kf], bk[nf][kf], sacc[mf][nf], 0, 0, 0);

    // online softmax (scores already scaled to log2 domain via Q)
#pragma unroll
    for (int mf = 0; mf < 2; ++mf) {
      float corr[4];
#pragma unroll
      for (int r = 0; r < 4; ++r) {
        float rm = fmaxf(fmaxf(sacc[mf][0][r], sacc[mf][1][r]),
                         fmaxf(sacc[mf][2][r], sacc[mf][3][r]));
#pragma unroll
        for (int off = 1; off < 16; off <<= 1) rm = fmaxf(rm, __shfl_xor(rm, off));
        float mn = fmaxf(mrun[mf][r], rm);
        corr[r] = exp2f(mrun[mf][r] - mn);
        mrun[mf][r] = mn;
      }
#pragma unroll
      for (int nf = 0; nf < 4; ++nf)
#pragma unroll
        for (int r = 0; r < 4; ++r) sacc[mf][nf][r] = exp2f(sacc[mf][nf][r] - mrun[mf][r]);
#pragma unroll
      for (int r = 0; r < 4; ++r) {  // deferred l: per-lane partial, reduced once at the end
        float ps = sacc[mf][0][r] + sacc[mf][1][r] + sacc[mf][2][r] + sacc[mf][3][r];
        lp[mf][r] = lp[mf][r] * corr[r] + ps;
      }
#pragma unroll
      for (int df = 0; df < 4; ++df)
#pragma unroll
        for (int r = 0; r < 4; ++r) oacc[mf][df][r] *= corr[r];
#pragma unroll
      for (int nf = 0; nf < 4; ++nf)
#pragma unroll
        for (int r = 0; r < 4; ++r)
          plds[w][mf * 16 + g4 * 4 + r][nf * 16 + r16] = f2bf(sacc[mf][nf][r]);
    }
    __syncthreads();

    bf16x8 ap[2][2], bv[2][4];
#pragma unroll
    for (int mf = 0; mf < 2; ++mf)
#pragma unroll
      for (int kf = 0; kf < 2; ++kf)
        ap[mf][kf] = *reinterpret_cast<const bf16x8*>(&plds[w][mf * 16 + r16][kf * 32 + g4 * 8]);
#pragma unroll
    for (int kf = 0; kf < 2; ++kf)
#pragma unroll
      for (int df = 0; df < 4; ++df)
        bv[kf][df] = *reinterpret_cast<const bf16x8*>(Vh + (size_t)(df * 16 + r16) * Tt + s0 +
                                                     kf * 32 + g4 * 8);
#pragma unroll
    for (int mf = 0; mf < 2; ++mf)
#pragma unroll
      for (int df = 0; df < 4; ++df)
#pragma unroll
        for (int kf = 0; kf < 2; ++kf)
          oacc[mf][df] =
              __builtin_amdgcn_mfma_f32_16x16x32_bf16(ap[mf][kf], bv[kf][df], oacc[mf][df], 0, 0, 0);
    __syncthreads();
  }

#pragma unroll
  for (int mf = 0; mf < 2; ++mf)
#pragma unroll
    for (int r = 0; r < 4; ++r) {
#pragma unroll
      for (int off = 1; off < 16; off <<= 1) lp[mf][r] += __shfl_xor(lp[mf][r], off);
    }
#pragma unroll
  for (int mf = 0; mf < 2; ++mf) {
    float inv[4];
#pragma unroll
    for (int r = 0; r < 4; ++r) inv[r] = 1.0f / lp[mf][r];
#pragma unroll
    for (int df = 0; df < 4; ++df)
#pragma unroll
      for (int r = 0; r < 4; ++r) {
        size_t trow = (size_t)(b * Tt + t0 + mf * 16 + g4 * 4 + r);
        Oa[trow * Dd + h * HD + df * 16 + r16] = f2bf(oacc[mf][df][r] * inv[r]);
      }
  }
}

// ---------------------------------------------------------------- launch
extern "C" void kernel_launch(void* const* d_in, const int* in_sizes, int n_in, void* d_out,
                              int out_size, void* d_ws, size_t ws_size, hipStream_t stream) {
  (void)in_sizes; (void)n_in; (void)out_size; (void)ws_size;
  const float* x = (const float*)d_in[0];
  const float* cosT = (const float*)d_in[1];
  const float* sinT = (const float*)d_in[2];
  const float* Wq = (const float*)d_in[3];
  const float* Wkv = (const float*)d_in[4];
  const float* Wo = (const float*)d_in[5];

  char* p = (char*)d_ws;
  u16* xb = (u16*)p;   p += (size_t)4096 * 1024 * 2;      // x bf16
  u16* wqkv = (u16*)p; p += (size_t)1536 * 1024 * 2;      // [Wq;Wkv] bf16
  u16* wob = (u16*)p;  p += (size_t)1024 * 1024 * 2;      // Wo bf16
  u16* Pbuf = (u16*)p; p += (size_t)4096 * 1536 * 2;      // qkv projection
  u16* Qb = (u16*)p;   p += (size_t)Bb * QH * Tt * HD * 2;
  u16* Kbuf = (u16*)p; p += (size_t)Bb * KVH * Tt * HD * 2;
  u16* Vtb = (u16*)p;  p += (size_t)Bb * KVH * HD * Tt * 2;
  u16* Ob = Pbuf;  // reuse: Pbuf dead after rope_scatter + v_transpose

  cvt_f32_to_bf16<<<4096, 256, 0, stream>>>(x, xb, 1048576);
  cvt_f32_to_bf16<<<1024, 256, 0, stream>>>(Wq, wqkv, 262144);
  cvt_f32_to_bf16<<<512, 256, 0, stream>>>(Wkv, wqkv + (size_t)1024 * 1024, 131072);
  cvt_f32_to_bf16<<<1024, 256, 0, stream>>>(Wo, wob, 262144);

  gemm_bt<false><<<dim3(12, 32), 256, 0, stream>>>(xb, wqkv, Pbuf, 4096, 1536, 1024);
  rope_scatter<<<10240, 256, 0, stream>>>(Pbuf, cosT, sinT, Qb, Kbuf);
  v_transpose<<<dim3(32, 8), 256, 0, stream>>>(Pbuf, Vtb);
  attn_fwd<<<dim3(16, 16, 2), 256, 0, stream>>>(Qb, Kbuf, Vtb, Ob);
  gemm_bt<true><<<dim3(8, 32), 256, 0, stream>>>(Ob, wob, d_out, 4096, 1024, 1024);
}

// Round 2
// 186.263 us; speedup vs baseline: 1.1828x; 1.1828x over previous
//
#include <hip/hip_runtime.h>

// GQA attention fused pipeline for MI355X (gfx950).
// cvt(fp32->bf16) -> GEMM(QKV proj) -> RoPE/scatter + V-transpose
// -> flash attention (swapped-operand 32x32 MFMA, barrier-free) -> GEMM(out proj).

typedef __bf16 bf16x8 __attribute__((ext_vector_type(8)));
typedef float f32x4 __attribute__((ext_vector_type(4)));
typedef float f32x16 __attribute__((ext_vector_type(16)));
typedef int i32x4 __attribute__((ext_vector_type(4)));
typedef unsigned short ushort4v __attribute__((ext_vector_type(4)));
typedef unsigned short ushort8v __attribute__((ext_vector_type(8)));
typedef unsigned short u16;
typedef unsigned int u32;

#define DEVINL __device__ __forceinline__

DEVINL float bf2f(u16 u) {
  unsigned int x = ((unsigned int)u) << 16;
  return __builtin_bit_cast(float, x);
}
DEVINL u16 f2bf(float f) {  // RTNE
  unsigned int x = __builtin_bit_cast(unsigned int, f);
  x += 0x7fffu + ((x >> 16) & 1u);
  return (u16)(x >> 16);
}

constexpr int Bb = 2, Tt = 2048, Dd = 1024, QH = 16, KVH = 4, HD = 64;
// fold softmax scale (1/sqrt(64)) and log2(e) into Q so we can use exp2f
constexpr float SCALE_L2E = 0.125f * 1.44269504088896340736f;

// ---------------------------------------------------------------- convert
__global__ void cvt_f32_to_bf16(const float* __restrict__ in, u16* __restrict__ out, int n4) {
  int i = blockIdx.x * blockDim.x + threadIdx.x;
  if (i >= n4) return;
  float4 v = reinterpret_cast<const float4*>(in)[i];
  ushort4v o = {f2bf(v.x), f2bf(v.y), f2bf(v.z), f2bf(v.w)};
  reinterpret_cast<ushort4v*>(out)[i] = o;
}

// ---------------------------------------------------------------- GEMM C = A(M,K) @ B(N,K)^T
// 128x128 tile, BK=64, 4 waves (each 64x64 = 4x4 frags of 16x16x32 bf16 MFMA).
template <bool OUT_F32>
__global__ __launch_bounds__(256) void gemm_bt(const u16* __restrict__ A,
                                               const u16* __restrict__ Bw,
                                               void* __restrict__ Cout, int M, int N, int K) {
  __shared__ alignas(16) u16 lA[128 * 64];
  __shared__ alignas(16) u16 lB[128 * 64];
  const int tid = threadIdx.x;
  const int w = tid >> 6, lane = tid & 63;
  const int r16 = lane & 15, g4 = lane >> 4;
  const int row0 = blockIdx.y * 128, col0 = blockIdx.x * 128;
  const int sr = tid >> 3, sc = tid & 7;
  const int NT = K >> 6;

  bf16x8 ra[4], rb[4];
  f32x4 acc[4][4];
#pragma unroll
  for (int i = 0; i < 4; ++i)
#pragma unroll
    for (int j = 0; j < 4; ++j) acc[i][j] = f32x4{0.f, 0.f, 0.f, 0.f};

  const int wm = (w >> 1) * 64, wn = (w & 1) * 64;

#pragma unroll
  for (int i = 0; i < 4; ++i) {
    int r = i * 32 + sr;
    ra[i] = *reinterpret_cast<const bf16x8*>(A + (size_t)(row0 + r) * K + sc * 8);
    rb[i] = *reinterpret_cast<const bf16x8*>(Bw + (size_t)(col0 + r) * K + sc * 8);
  }

  for (int kt = 0; kt < NT; ++kt) {
    __syncthreads();
#pragma unroll
    for (int i = 0; i < 4; ++i) {
      int r = i * 32 + sr;
      int c = (sc ^ (r & 7)) * 8;
      *reinterpret_cast<bf16x8*>(&lA[r * 64 + c]) = ra[i];
      *reinterpret_cast<bf16x8*>(&lB[r * 64 + c]) = rb[i];
    }
    __syncthreads();
    if (kt + 1 < NT) {
      int k0 = (kt + 1) << 6;
#pragma unroll
      for (int i = 0; i < 4; ++i) {
        int r = i * 32 + sr;
        ra[i] = *reinterpret_cast<const bf16x8*>(A + (size_t)(row0 + r) * K + k0 + sc * 8);
        rb[i] = *reinterpret_cast<const bf16x8*>(Bw + (size_t)(col0 + r) * K + k0 + sc * 8);
      }
    }
#pragma unroll
    for (int kk = 0; kk < 2; ++kk) {
      bf16x8 af[4], bfr[4];
#pragma unroll
      for (int mf = 0; mf < 4; ++mf) {
        int r = wm + mf * 16 + r16;
        int c = ((kk * 4 + g4) ^ (r & 7)) * 8;
        af[mf] = *reinterpret_cast<const bf16x8*>(&lA[r * 64 + c]);
      }
#pragma unroll
      for (int nf = 0; nf < 4; ++nf) {
        int r = wn + nf * 16 + r16;
        int c = ((kk * 4 + g4) ^ (r & 7)) * 8;
        bfr[nf] = *reinterpret_cast<const bf16x8*>(&lB[r * 64 + c]);
      }
#pragma unroll
      for (int mf = 0; mf < 4; ++mf)
#pragma unroll
        for (int nf = 0; nf < 4; ++nf)
          acc[mf][nf] =
              __builtin_amdgcn_mfma_f32_16x16x32_bf16(af[mf], bfr[nf], acc[mf][nf], 0, 0, 0);
    }
  }

#pragma unroll
  for (int mf = 0; mf < 4; ++mf)
#pragma unroll
    for (int nf = 0; nf < 4; ++nf)
#pragma unroll
      for (int r = 0; r < 4; ++r) {
        size_t row = (size_t)(row0 + wm + mf * 16 + g4 * 4 + r);
        size_t col = (size_t)(col0 + wn + nf * 16 + r16);
        float v = acc[mf][nf][r];
        if (OUT_F32)
          reinterpret_cast<float*>(Cout)[row * N + col] = v;
        else
          reinterpret_cast<u16*>(Cout)[row * N + col] = f2bf(v);
      }
}

// ---------------------------------------------------------------- RoPE + scatter (q and k)
__global__ void rope_scatter(const u16* __restrict__ P, const float* __restrict__ cosT,
                             const float* __restrict__ sinT, u16* __restrict__ Q,
                             u16* __restrict__ Kc) {
  int idx = blockIdx.x * 256 + threadIdx.x;
  if (idx >= (Bb * Tt) * 640) return;
  int row = idx / 640, p = idx - row * 640;
  int b = row >> 11, t = row & 2047;
  int n, d;
  u16* outp;
  float scl;
  if (p < 512) {
    n = p * 2;
    int h = n >> 6;
    d = n & 63;
    outp = Q + ((size_t)(b * QH + h) * Tt + t) * HD + d;
    scl = SCALE_L2E;
  } else {
    int r2 = p - 512;
    int kvh = r2 >> 5, dp = r2 & 31;
    d = dp * 2;
    n = 1024 + kvh * 128 + d;
    outp = Kc + ((size_t)(b * KVH + kvh) * Tt + t) * HD + d;
    scl = 1.0f;
  }
  unsigned int pv = *reinterpret_cast<const unsigned int*>(P + (size_t)row * 1536 + n);
  float v0 = bf2f((u16)(pv & 0xffffu)), v1 = bf2f((u16)(pv >> 16));
  float c = cosT[t * HD + d], s = sinT[t * HD + d];
  float o0 = (v0 * c - v1 * s) * scl;
  float o1 = (v1 * c + v0 * s) * scl;
  unsigned int ob = (unsigned int)f2bf(o0) | ((unsigned int)f2bf(o1) << 16);
  *reinterpret_cast<unsigned int*>(outp) = ob;
}

// ---------------------------------------------------------------- V transpose: Vt[bh][d][t]
__global__ void v_transpose(const u16* __restrict__ P, u16* __restrict__ Vt) {
  __shared__ u16 tile[64][72];
  int bh = blockIdx.y;
  int b = bh >> 2, kvh = bh & 3;
  int t0 = blockIdx.x * 64;
  int tid = threadIdx.x;
  int colbase = 1024 + kvh * 128 + 64;
#pragma unroll
  for (int j = 0; j < 4; ++j) {
    int rr = j * 16 + (tid >> 4);
    int cc = (tid & 15) * 4;
    *reinterpret_cast<uint2*>(&tile[rr][cc]) =
        *reinterpret_cast<const uint2*>(P + (size_t)(b * Tt + t0 + rr) * 1536 + colbase + cc);
  }
  __syncthreads();
  int d = tid >> 2, seg = tid & 3;
  size_t obase = ((size_t)bh * HD + d) * Tt + t0 + seg * 16;
#pragma unroll
  for (int jj = 0; jj < 2; ++jj) {
    ushort8v v;
#pragma unroll
    for (int i = 0; i < 8; ++i) v[i] = tile[seg * 16 + jj * 8 + i][d];
    *reinterpret_cast<ushort8v*>(Vt + obase + jj * 8) = v;
  }
}

// ---------------------------------------------------------------- flash attention v2
// Swapped-operand structure (guide §B): per wave 32 q-rows; S^T = mfma(K, Q) so
// lane's column t = lane&31 and softmax reduce is in-lane + one shfl_xor(32);
// O^T = mfma(Vt, P^T) so corr/l/m stay per-lane scalars. No barriers, no LDS in
// main loop. P repacked to B-frag layout via v_cvt_pk_bf16_f32 + half-exchange.
__global__ __launch_bounds__(256) void attn_fwd2(const u16* __restrict__ Q,
                                                 const u16* __restrict__ Kc,
                                                 const u16* __restrict__ Vt,
                                                 u16* __restrict__ Oa) {
  __shared__ alignas(16) u16 ot[4][32][72];  // epilogue transpose only
  const int tid = threadIdx.x;
  const int w = tid >> 6, lane = tid & 63;
  const int l31 = lane & 31, hi = lane >> 5;
  const int h = blockIdx.y, b = blockIdx.z;
  const int kvh = h >> 2;
  const int t0 = blockIdx.x * 128 + w * 32;

  const u16* Qh = Q + ((size_t)(b * QH + h) * Tt + t0 + l31) * HD + hi * 8;
  const u16* Kh = Kc + (size_t)(b * KVH + kvh) * Tt * HD;
  const u16* Vh = Vt + (size_t)(b * KVH + kvh) * HD * Tt;

  // Q as B-fragment: col=lane&31 = t, k = kf*16 + hi*8 + j  (Q pre-scaled)
  bf16x8 qf[4];
#pragma unroll
  for (int kf = 0; kf < 4; ++kf)
    qf[kf] = *reinterpret_cast<const bf16x8*>(Qh + kf * 16);

  f32x16 oacc[2];
#pragma unroll
  for (int df = 0; df < 2; ++df)
#pragma unroll
    for (int r = 0; r < 16; ++r) oacc[df][r] = 0.f;
  float mrun = -__builtin_inff(), lp = 0.f;

  for (int s0 = 0; s0 < Tt; s0 += 64) {
    // K as A-fragment: row = s-local = lane&31 (+sb*32), k = kf*16 + hi*8 + j
    bf16x8 kfr[2][4];
#pragma unroll
    for (int sb = 0; sb < 2; ++sb) {
      const u16* Kb = Kh + (size_t)(s0 + sb * 32 + l31) * HD + hi * 8;
#pragma unroll
      for (int kf = 0; kf < 4; ++kf)
        kfr[sb][kf] = *reinterpret_cast<const bf16x8*>(Kb + kf * 16);
    }
    f32x16 sacc[2];
#pragma unroll
    for (int sb = 0; sb < 2; ++sb) {
#pragma unroll
      for (int r = 0; r < 16; ++r) sacc[sb][r] = 0.f;
#pragma unroll
      for (int kf = 0; kf < 4; ++kf)
        sacc[sb] = __builtin_amdgcn_mfma_f32_32x32x16_bf16(kfr[sb][kf], qf[kf], sacc[sb], 0, 0, 0);
    }

    // V loads issued early: latency hides under softmax below.
    // Vt as A-fragment: row = d = df*32 + lane&31, k = s-local
    bf16x8 vf[2][2][2];  // [df][sb][ks]
#pragma unroll
    for (int df = 0; df < 2; ++df)
#pragma unroll
      for (int sb = 0; sb < 2; ++sb)
#pragma unroll
        for (int ks = 0; ks < 2; ++ks)
          vf[df][sb][ks] = *reinterpret_cast<const bf16x8*>(
              Vh + (size_t)(df * 32 + l31) * Tt + s0 + sb * 32 + ks * 16 + hi * 8);

    // ---- online softmax, fully per-lane (column t = lane&31) ----
    float m0, m1, m2, m3;
    m0 = fmaxf(sacc[0][0], sacc[0][1]);  m1 = fmaxf(sacc[0][2], sacc[0][3]);
    m2 = fmaxf(sacc[0][4], sacc[0][5]);  m3 = fmaxf(sacc[0][6], sacc[0][7]);
#pragma unroll
    for (int r = 8; r < 16; r += 4) {
      m0 = fmaxf(m0, fmaxf(sacc[0][r], sacc[0][r + 1]));
      m1 = fmaxf(m1, fmaxf(sacc[0][r + 2], sacc[0][r + 3]));
    }
#pragma unroll
    for (int r = 0; r < 16; r += 4) {
      m2 = fmaxf(m2, fmaxf(sacc[1][r], sacc[1][r + 1]));
      m3 = fmaxf(m3, fmaxf(sacc[1][r + 2], sacc[1][r + 3]));
    }
    float tm = fmaxf(fmaxf(m0, m1), fmaxf(m2, m3));
    tm = fmaxf(tm, __shfl_xor(tm, 32));  // other lane-half holds the other 32 s
    float mn = fmaxf(mrun, tm);
    float corr = exp2f(mrun - mn);
    mrun = mn;

    float a0 = 0.f, a1 = 0.f, a2 = 0.f, a3 = 0.f;
#pragma unroll
    for (int sb = 0; sb < 2; ++sb)
#pragma unroll
      for (int r = 0; r < 16; r += 4) {
        float e0 = exp2f(sacc[sb][r] - mn);
        float e1 = exp2f(sacc[sb][r + 1] - mn);
        float e2 = exp2f(sacc[sb][r + 2] - mn);
        float e3 = exp2f(sacc[sb][r + 3] - mn);
        sacc[sb][r] = e0; sacc[sb][r + 1] = e1; sacc[sb][r + 2] = e2; sacc[sb][r + 3] = e3;
        a0 += e0; a1 += e1; a2 += e2; a3 += e3;
      }
    lp = lp * corr + ((a0 + a1) + (a2 + a3));
#pragma unroll
    for (int df = 0; df < 2; ++df)
#pragma unroll
      for (int r = 0; r < 16; ++r) oacc[df][r] *= corr;

    // ---- pack P to B-frag layout: k = ks*16 + hi*8 + j consecutive s ----
    bf16x8 pf[2][2];  // [sb][ks]
#pragma unroll
    for (int sb = 0; sb < 2; ++sb) {
      u32 pw[8];
#pragma unroll
      for (int r2 = 0; r2 < 8; ++r2) {
        u32 o;
        asm("v_cvt_pk_bf16_f32 %0, %1, %2"
            : "=v"(o)
            : "v"(sacc[sb][2 * r2]), "v"(sacc[sb][2 * r2 + 1]));
        pw[r2] = o;
      }
      u32 fw[2][4];
#pragma unroll
      for (int pp = 0; pp < 4; ++pp) {
        int ks = pp >> 1, o = pp & 1;
        u32 a = pw[ks * 4 + o], bq = pw[ks * 4 + o + 2];
        u32 ax = __shfl_xor(a, 32), bx = __shfl_xor(bq, 32);
        fw[ks][o] = hi ? bx : a;       // k = hi*8 + {2o, 2o+1}
        fw[ks][o + 2] = hi ? bq : ax;  // k = hi*8 + {4+2o, 5+2o}
      }
#pragma unroll
      for (int ks = 0; ks < 2; ++ks) {
        i32x4 iv = {(int)fw[ks][0], (int)fw[ks][1], (int)fw[ks][2], (int)fw[ks][3]};
        pf[sb][ks] = __builtin_bit_cast(bf16x8, iv);
      }
    }

    // ---- O^T += Vt * P^T ----
#pragma unroll
    for (int df = 0; df < 2; ++df)
#pragma unroll
      for (int sb = 0; sb < 2; ++sb)
#pragma unroll
        for (int ks = 0; ks < 2; ++ks)
          oacc[df] =
              __builtin_amdgcn_mfma_f32_32x32x16_bf16(vf[df][sb][ks], pf[sb][ks], oacc[df], 0, 0, 0);
  }

  // ---- epilogue: normalize, transpose O^T -> O via per-wave LDS, store ----
  lp += __shfl_xor(lp, 32);
  float inv = 1.0f / lp;
#pragma unroll
  for (int df = 0; df < 2; ++df)
#pragma unroll
    for (int r = 0; r < 16; ++r) {
      int d = df * 32 + (r & 3) + 8 * (r >> 2) + 4 * hi;
      ot[w][l31][d] = f2bf(oacc[df][r] * inv);
    }
  __syncthreads();  // ensures LDS writes visible (also covers cross-lane in-wave)
  {
    int tr = lane >> 1, dblk = (lane & 1) * 32;
    u16* gdst = Oa + ((size_t)(b * Tt + t0 + tr)) * Dd + h * HD + dblk;
#pragma unroll
    for (int c = 0; c < 4; ++c) {
      ushort8v vv = *reinterpret_cast<const ushort8v*>(&ot[w][tr][dblk + c * 8]);
      *reinterpret_cast<ushort8v*>(gdst + c * 8) = vv;
    }
  }
}

// ---------------------------------------------------------------- launch
extern "C" void kernel_launch(void* const* d_in, const int* in_sizes, int n_in, void* d_out,
                              int out_size, void* d_ws, size_t ws_size, hipStream_t stream) {
  (void)in_sizes; (void)n_in; (void)out_size; (void)ws_size;
  const float* x = (const float*)d_in[0];
  const float* cosT = (const float*)d_in[1];
  const float* sinT = (const float*)d_in[2];
  const float* Wq = (const float*)d_in[3];
  const float* Wkv = (const float*)d_in[4];
  const float* Wo = (const float*)d_in[5];

  char* p = (char*)d_ws;
  u16* xb = (u16*)p;   p += (size_t)4096 * 1024 * 2;
  u16* wqkv = (u16*)p; p += (size_t)1536 * 1024 * 2;
  u16* wob = (u16*)p;  p += (size_t)1024 * 1024 * 2;
  u16* Pbuf = (u16*)p; p += (size_t)4096 * 1536 * 2;
  u16* Qb = (u16*)p;   p += (size_t)Bb * QH * Tt * HD * 2;
  u16* Kbuf = (u16*)p; p += (size_t)Bb * KVH * Tt * HD * 2;
  u16* Vtb = (u16*)p;  p += (size_t)Bb * KVH * HD * Tt * 2;
  u16* Ob = Pbuf;  // Pbuf dead after rope_scatter + v_transpose

  cvt_f32_to_bf16<<<4096, 256, 0, stream>>>(x, xb, 1048576);
  cvt_f32_to_bf16<<<1024, 256, 0, stream>>>(Wq, wqkv, 262144);
  cvt_f32_to_bf16<<<512, 256, 0, stream>>>(Wkv, wqkv + (size_t)1024 * 1024, 131072);
  cvt_f32_to_bf16<<<1024, 256, 0, stream>>>(Wo, wob, 262144);

  gemm_bt<false><<<dim3(12, 32), 256, 0, stream>>>(xb, wqkv, Pbuf, 4096, 1536, 1024);
  rope_scatter<<<10240, 256, 0, stream>>>(Pbuf, cosT, sinT, Qb, Kbuf);
  v_transpose<<<dim3(32, 8), 256, 0, stream>>>(Pbuf, Vtb);
  attn_fwd2<<<dim3(16, 16, 2), 256, 0, stream>>>(Qb, Kbuf, Vtb, Ob);
  gemm_bt<true><<<dim3(8, 32), 256, 0, stream>>>(Ob, wob, d_out, 4096, 1024, 1024);
}